// Round 2
// baseline (402.508 us; speedup 1.0000x reference)
//
#include <hip/hip_runtime.h>
#include <hip/hip_bf16.h>

// GAT layer, fused. fp32 in/out, bf16 MFMA internally.
// B=65536, N=2, F=256, H=4, D=256, mean over heads.
// v3: barrier-free phase 3 (in-register A-frag build, 2x2 wave split),
// XOR-swizzled sH (no bank conflicts, no pad), PT B-frags from L2,
// adj prefetched. 3 barriers/block total (was 19). LDS 38912 B.

typedef __attribute__((ext_vector_type(8))) short short8;
typedef __attribute__((ext_vector_type(4))) float floatx4;

__device__ __forceinline__ float bf2f(short u) {
    union { unsigned int i; float f; } v;
    v.i = ((unsigned int)(unsigned short)u) << 16;
    return v.f;
}
// pack two fp32 -> one u32 of 2 bf16 (RNE), low = first
__device__ __forceinline__ unsigned int pk2(float lo, float hi) {
    __hip_bfloat162 t = __float22bfloat162_rn(make_float2(lo, hi));
    union { __hip_bfloat162 h; unsigned int u; } cv; cv.h = t;
    return cv.u;
}

// ---- fused prep ----
// blocks [0,1024): Wt2[((hh*8+j)*256 + d)*32 + kl] = bf16(W[(j*32+kl)*1024 + hh*256 + d])
//   (fragment-ordered: a B-frag wave load is 1KB contiguous)
// blocks [1024,1536): one wave per dot-product PT[n][k], n = half*4+h
__global__ void gat_prep(const float* __restrict__ W, const float* __restrict__ a,
                         __hip_bfloat16* __restrict__ PT,
                         __hip_bfloat16* __restrict__ Wt2) {
    int b = blockIdx.x;
    if (b < 1024) {
        int idx = b * 256 + threadIdx.x;          // 262144, coalesced W reads
        int d = idx & 255, hh = (idx >> 8) & 3, k = idx >> 10;
        int j = k >> 5, kl = k & 31;
        Wt2[(((hh * 8 + j) * 256 + d) << 5) + kl] =
            __float2bfloat16(W[k * 1024 + hh * 256 + d]);
    } else {
        int wid = (b - 1024) * 4 + (threadIdx.x >> 6);   // 2048 waves
        int lane = threadIdx.x & 63;
        int k = wid & 255, h = (wid >> 8) & 3, half = wid >> 10;
        float4 wv = *(const float4*)(W + k * 1024 + h * 256 + lane * 4);
        float4 av = *(const float4*)(a + h * 512 + half * 256 + lane * 4);
        float s = wv.x * av.x + wv.y * av.y + wv.z * av.z + wv.w * av.w;
        #pragma unroll
        for (int off = 32; off; off >>= 1) s += __shfl_down(s, off);
        if (lane == 0) PT[(half * 4 + h) * 256 + k] = __float2bfloat16(s);
        if (lane == 1) PT[2048 + wid] = __float2bfloat16(0.f);  // zero rows 8..15
    }
}

#define TB 32          // batches per block -> 64 rows
#define ROWS 64

__global__ __launch_bounds__(256, 3)
void gat_main(const float* __restrict__ hin,
              const int* __restrict__ adj,
              const __hip_bfloat16* __restrict__ PT,
              const __hip_bfloat16* __restrict__ Wt2,
              float* __restrict__ out) {
    __shared__ __align__(16) short sH[ROWS * 256];     // 32768 B, XOR-swizzled
    __shared__ __align__(16) float sS[ROWS][16];       //  4096 B
    __shared__ __align__(16) float2 sC[TB * 4 * 2];    //  2048 B

    const int tid = threadIdx.x;
    const int lane = tid & 63;
    const int wave = tid >> 6;
    const int m = lane & 15;     // MFMA row/col index
    const int q = lane >> 4;     // MFMA quad
    const long batch0 = (long)blockIdx.x * TB;
    char* sHb = (char*)sH;

    // prefetch adj for phase 2 (latency hides under staging + phase 1)
    int4 av = ((const int4*)adj)[batch0 + (tid >> 3)];

    // stage H tile: 64 rows x 256 fp32 -> bf16, XOR-swizzled LDS
    // swizzle: byte_off_in_row ^= (row&7)<<4  (16B-granular, bijective)
    {
        const float4* gh = (const float4*)(hin + batch0 * 512);
        #pragma unroll
        for (int it = 0; it < 16; ++it) {
            int idx = tid + it * 256;       // 4096 float4 per block
            int r = idx >> 6, c4 = idx & 63;
            float4 v = gh[idx];
            uint2 bv;
            bv.x = pk2(v.x, v.y);
            bv.y = pk2(v.z, v.w);
            *(uint2*)(sHb + r * 512 + ((c4 * 8) ^ ((r & 7) << 4))) = bv;
        }
    }
    __syncthreads();

    // phase 1: S = H(64x256) @ P^T(256x16); B-frags straight from L2-hot PT
    {
        const short* ptg = (const short*)PT;
        int row = wave * 16 + m;
        floatx4 a0 = {0.f, 0.f, 0.f, 0.f};
        #pragma unroll
        for (int ks = 0; ks < 8; ++ks) {
            short8 bf = *(const short8*)(ptg + m * 256 + ks * 32 + q * 8);
            short8 f0 = *(const short8*)(sHb + row * 512 +
                          ((ks * 64 + q * 16) ^ ((row & 7) << 4)));
            a0 = __builtin_amdgcn_mfma_f32_16x16x32_bf16(f0, bf, a0, 0, 0, 0);
        }
        #pragma unroll
        for (int r = 0; r < 4; ++r)       // C-layout: col=lane&15, row=q*4+r
            sS[wave * 16 + q * 4 + r][m] = a0[r];
    }
    __syncthreads();

    // phase 2: masked 2-way softmax -> c = attn/4. thread = (batch, head, row)
    {
        int lb = tid >> 3, hh = (tid >> 1) & 3, i = tid & 1;
        int m0 = i ? av.z : av.x, m1 = i ? av.w : av.y;
        float s  = sS[lb * 2 + i][hh];
        float t0 = sS[lb * 2][4 + hh], t1 = sS[lb * 2 + 1][4 + hh];
        float e0 = s + t0; e0 = e0 >= 0.f ? e0 : 0.2f * e0;
        float e1 = s + t1; e1 = e1 >= 0.f ? e1 : 0.2f * e1;
        e0 = fminf(fmaxf(e0, -80.f), 80.f);
        e1 = fminf(fmaxf(e1, -80.f), 80.f);
        bool k0 = m0 > 0, k1 = m1 > 0;    // diag forced 1 by setup
        float f0 = k0 ? e0 : -1e30f, f1 = k1 ? e1 : -1e30f;
        float mx = fmaxf(f0, f1);
        float p0 = k0 ? __expf(e0 - mx) : 0.f;
        float p1 = k1 ? __expf(e1 - mx) : 0.f;
        float den = p0 + p1;
        float inv = den > 1e-30f ? 0.25f / den : 0.f;
        sC[(lb * 4 + hh) * 2 + i] = make_float2(p0 * inv, p1 * inv);
    }
    __syncthreads();

    // phase 3 (barrier-free): out(64x256) = Z(64x1024) @ W(1024x256)
    // wave = (wr,wc): rows [wr*32, wr*32+32), cols [wc*128, wc*128+128)
    // A-frags built in registers from sH + per-lane c; B-frags from L2 Wt2.
    const int wr = wave >> 1, wc = wave & 1;

    float2 c2[2][4];
    #pragma unroll
    for (int mt = 0; mt < 2; ++mt)
        #pragma unroll
        for (int hh = 0; hh < 4; ++hh) {
            int zr = wr * 32 + mt * 16 + m;
            c2[mt][hh] = sC[((zr >> 1) * 4 + hh) * 2 + (zr & 1)];
        }

    floatx4 acc[2][8];
    #pragma unroll
    for (int i = 0; i < 2; ++i)
        #pragma unroll
        for (int j = 0; j < 8; ++j)
            acc[i][j] = (floatx4){0.f, 0.f, 0.f, 0.f};

    #pragma unroll 1
    for (int js = 0; js < 8; ++js) {
        // per-wave H row-pair fragments (reused across all 4 heads)
        short8 v0[2], v1[2];
        #pragma unroll
        for (int mt = 0; mt < 2; ++mt) {
            int hr = wr * 32 + mt * 16 + (m & ~1);
            int co = js * 64 + q * 16;
            v0[mt] = *(const short8*)(sHb + hr * 512 + (co ^ ((hr & 7) << 4)));
            v1[mt] = *(const short8*)(sHb + (hr + 1) * 512 + (co ^ (((hr + 1) & 7) << 4)));
        }
        float f0[2][8], f1[2][8];
        #pragma unroll
        for (int mt = 0; mt < 2; ++mt)
            #pragma unroll
            for (int e = 0; e < 8; ++e) {
                f0[mt][e] = bf2f(v0[mt][e]);
                f1[mt][e] = bf2f(v1[mt][e]);
            }
        #pragma unroll
        for (int hh = 0; hh < 4; ++hh) {
            // build A-frags: z = c0*h0 + c1*h1, packed bf16
            union { short8 s; unsigned int u[4]; } fr[2];
            #pragma unroll
            for (int mt = 0; mt < 2; ++mt)
                #pragma unroll
                for (int p = 0; p < 4; ++p) {
                    float z0 = c2[mt][hh].x * f0[mt][p * 2]     + c2[mt][hh].y * f1[mt][p * 2];
                    float z1 = c2[mt][hh].x * f0[mt][p * 2 + 1] + c2[mt][hh].y * f1[mt][p * 2 + 1];
                    fr[mt].u[p] = pk2(z0, z1);
                }
            const short* wbase = (const short*)Wt2 + (((hh * 8 + js) * 256 + wc * 128) << 5);
            #pragma unroll
            for (int ntg = 0; ntg < 2; ++ntg) {
                short8 bfr[4];
                #pragma unroll
                for (int nt = 0; nt < 4; ++nt)
                    bfr[nt] = *(const short8*)(wbase + (((ntg * 4 + nt) * 16 + m) << 5) + q * 8);
                #pragma unroll
                for (int nt = 0; nt < 4; ++nt)
                    #pragma unroll
                    for (int mt = 0; mt < 2; ++mt)
                        acc[mt][ntg * 4 + nt] = __builtin_amdgcn_mfma_f32_16x16x32_bf16(
                            fr[mt].s, bfr[nt], acc[mt][ntg * 4 + nt], 0, 0, 0);
            }
        }
    }

    // epilogue: direct fp32 stores, 16 lanes = 64B contiguous per instruction
    {
        float* og = out + batch0 * 512;
        #pragma unroll
        for (int mt = 0; mt < 2; ++mt)
            #pragma unroll
            for (int nt = 0; nt < 8; ++nt) {
                int col = wc * 128 + nt * 16 + m;
                #pragma unroll
                for (int r = 0; r < 4; ++r)
                    og[(wr * 32 + mt * 16 + q * 4 + r) * 256 + col] = acc[mt][nt][r];
            }
    }
}

extern "C" void kernel_launch(void* const* d_in, const int* in_sizes, int n_in,
                              void* d_out, int out_size, void* d_ws, size_t ws_size,
                              hipStream_t stream) {
    const float* hin = (const float*)d_in[0];
    const int* adj   = (const int*)d_in[1];
    const float* W   = (const float*)d_in[2];
    const float* a   = (const float*)d_in[3];
    float* out       = (float*)d_out;

    __hip_bfloat16* PT  = (__hip_bfloat16*)d_ws;  // 16*256 bf16 = 8 KB
    __hip_bfloat16* Wt2 = PT + 16 * 256;          // 32*256*32 bf16 = 512 KB

    // ws guard: leaves out poisoned -> diagnostic, not corruption
    if (ws_size < (16 * 256 + 256 * 1024) * sizeof(__hip_bfloat16)) return;

    int B = in_sizes[0] / 512;                    // 65536
    gat_prep<<<1536, 256, 0, stream>>>(W, a, PT, Wt2);
    gat_main<<<B / TB, 256, 0, stream>>>(hin, adj, PT, Wt2, out);
}

// Round 3
// 291.293 us; speedup vs baseline: 1.3818x; 1.3818x over previous
//
#include <hip/hip_runtime.h>
#include <hip/hip_bf16.h>

// GAT layer, fused. fp32 in/out, bf16 MFMA internally.
// B=65536, N=2, F=256, H=4, D=256, mean over heads.
// v4: v2 structure + (a) single-barrier pipelined phase 3 with double-buffered
// 64-K sZ chunks (B-loads || Zbuild(next) || MFMA(cur) in each interval),
// (b) XOR-swizzled sH/sZ (bank-conflict-free, no pads), (c) PT/adj prefetched
// into regs, sPT staging removed. LDS 51200 B -> 3 blocks/CU. ~145 VGPR.

typedef __attribute__((ext_vector_type(8))) short short8;
typedef __attribute__((ext_vector_type(4))) float floatx4;

__device__ __forceinline__ float bf2f(short u) {
    union { unsigned int i; float f; } v;
    v.i = ((unsigned int)(unsigned short)u) << 16;
    return v.f;
}
// pack two fp32 -> one u32 of 2 bf16 (RNE), low = first
__device__ __forceinline__ unsigned int pk2(float lo, float hi) {
    __hip_bfloat162 t = __float22bfloat162_rn(make_float2(lo, hi));
    union { __hip_bfloat162 h; unsigned int u; } cv; cv.h = t;
    return cv.u;
}

// ---- fused prep ----
// blocks [0,1024): Wt2[((hh*8+j)*256 + d)*32 + kl] = bf16(W[(j*32+kl)*1024 + hh*256 + d])
//   (fragment-ordered: a B-frag wave load is 1KB contiguous)
// blocks [1024,1536): one wave per dot-product PT[n][k], n = half*4+h
__global__ void gat_prep(const float* __restrict__ W, const float* __restrict__ a,
                         __hip_bfloat16* __restrict__ PT,
                         __hip_bfloat16* __restrict__ Wt2) {
    int b = blockIdx.x;
    if (b < 1024) {
        int idx = b * 256 + threadIdx.x;          // 262144, coalesced W reads
        int d = idx & 255, hh = (idx >> 8) & 3, k = idx >> 10;
        int j = k >> 5, kl = k & 31;
        Wt2[(((hh * 8 + j) * 256 + d) << 5) + kl] =
            __float2bfloat16(W[k * 1024 + hh * 256 + d]);
    } else {
        int wid = (b - 1024) * 4 + (threadIdx.x >> 6);   // 2048 waves
        int lane = threadIdx.x & 63;
        int k = wid & 255, h = (wid >> 8) & 3, half = wid >> 10;
        float4 wv = *(const float4*)(W + k * 1024 + h * 256 + lane * 4);
        float4 av = *(const float4*)(a + h * 512 + half * 256 + lane * 4);
        float s = wv.x * av.x + wv.y * av.y + wv.z * av.z + wv.w * av.w;
        #pragma unroll
        for (int off = 32; off; off >>= 1) s += __shfl_down(s, off);
        if (lane == 0) PT[(half * 4 + h) * 256 + k] = __float2bfloat16(s);
        if (lane == 1) PT[2048 + wid] = __float2bfloat16(0.f);  // zero rows 8..15
    }
}

#define TB 32          // batches per block -> 64 rows
#define ROWS 64

__global__ __launch_bounds__(256, 3)
void gat_main(const float* __restrict__ hin,
              const int* __restrict__ adj,
              const __hip_bfloat16* __restrict__ PT,
              const __hip_bfloat16* __restrict__ Wt2,
              float* __restrict__ out) {
    __shared__ __align__(16) short sH[ROWS * 256];   // 32768 B, XOR-swizzled
    __shared__ __align__(16) short sZd[2][ROWS * 64];// 2 x 8192 B, XOR-swizzled
    __shared__ __align__(16) float2 sC[TB * 4 * 2];  //  2048 B
    // sS (64x16 f32 = 4096 B) unioned into sZd[1] (dead until loop iter 0)
    float (*sS)[16] = (float (*)[16])(&sZd[1][0]);

    const int tid = threadIdx.x;
    const int lane = tid & 63;
    const int wave = tid >> 6;
    const int m = lane & 15;     // MFMA row/col index
    const int q = lane >> 4;     // MFMA quad
    const long batch0 = (long)blockIdx.x * TB;
    char* sHb = (char*)sH;
    char* sZb = (char*)sZd;

    // prefetch phase-1 B-frags (PT, L2-hot) and adj; latency hides under staging
    short8 ptf[8];
    {
        const short* ptg = (const short*)PT;
        #pragma unroll
        for (int ks = 0; ks < 8; ++ks)
            ptf[ks] = *(const short8*)(ptg + m * 256 + ks * 32 + q * 8);
    }
    int4 av = ((const int4*)adj)[batch0 + (tid >> 3)];

    // stage H tile: 64 rows x 256 fp32 -> bf16, XOR-swizzled LDS
    // swizzle: byte_off_in_row ^= (row&7)<<4  (16B-granular, bijective)
    {
        const float4* gh = (const float4*)(hin + batch0 * 512);
        #pragma unroll
        for (int it = 0; it < 16; ++it) {
            int idx = tid + it * 256;       // 4096 float4 per block
            int r = idx >> 6, c4 = idx & 63;
            float4 v = gh[idx];
            uint2 bv;
            bv.x = pk2(v.x, v.y);
            bv.y = pk2(v.z, v.w);
            *(uint2*)(sHb + r * 512 + ((c4 * 8) ^ ((r & 7) << 4))) = bv;
        }
    }
    __syncthreads();

    // phase 1: S = H(64x256) @ P^T(256x16), one M-tile per wave
    {
        int row = wave * 16 + m;
        floatx4 a0 = {0.f, 0.f, 0.f, 0.f};
        #pragma unroll
        for (int ks = 0; ks < 8; ++ks) {
            short8 f0 = *(const short8*)(sHb + row * 512 +
                          ((ks * 64 + q * 16) ^ ((row & 7) << 4)));
            a0 = __builtin_amdgcn_mfma_f32_16x16x32_bf16(f0, ptf[ks], a0, 0, 0, 0);
        }
        #pragma unroll
        for (int r = 0; r < 4; ++r)       // C-layout: col=lane&15, row=q*4+r
            sS[wave * 16 + q * 4 + r][m] = a0[r];
    }
    __syncthreads();

    // phase 2: masked 2-way softmax -> c = attn/4. thread = (batch, head, row)
    {
        int lb = tid >> 3, hh = (tid >> 1) & 3, i = tid & 1;
        int m0 = i ? av.z : av.x, m1 = i ? av.w : av.y;
        float s  = sS[lb * 2 + i][hh];
        float t0 = sS[lb * 2][4 + hh], t1 = sS[lb * 2 + 1][4 + hh];
        float e0 = s + t0; e0 = e0 >= 0.f ? e0 : 0.2f * e0;
        float e1 = s + t1; e1 = e1 >= 0.f ? e1 : 0.2f * e1;
        e0 = fminf(fmaxf(e0, -80.f), 80.f);
        e1 = fminf(fmaxf(e1, -80.f), 80.f);
        bool k0 = m0 > 0, k1 = m1 > 0;    // diag forced 1 by setup
        float f0 = k0 ? e0 : -1e30f, f1 = k1 ? e1 : -1e30f;
        float mx = fmaxf(f0, f1);
        float p0 = k0 ? __expf(e0 - mx) : 0.f;
        float p1 = k1 ? __expf(e1 - mx) : 0.f;
        float den = p0 + p1;
        float inv = den > 1e-30f ? 0.25f / den : 0.f;
        sC[(lb * 4 + hh) * 2 + i] = make_float2(p0 * inv, p1 * inv);
    }
    __syncthreads();

    // phase 3: out(64x256) = sum over 16 chunks of Z_ch(64x64) @ W_ch(64x256).
    // chunk ch: head hh=ch>>2, 64-K slice kc=ch&3. Double-buffered sZ, ONE
    // barrier per chunk: interval = {B-loads(ch) ; Zbuild(ch+1) ; MFMA(ch)}.
    const int zg = tid & 7, zrb = tid >> 3;   // Zbuild thread mapping

    #define ZBUILD(ch, buf)                                                     \
    {                                                                           \
        int hh_ = (ch) >> 2, kc_ = (ch) & 3;                                    \
        _Pragma("unroll")                                                       \
        for (int half = 0; half < 2; ++half) {                                  \
            int zr = zrb + half * 32;                                           \
            float2 c = sC[((zr >> 1) * 4 + hh_) * 2 + (zr & 1)];                \
            int hr = zr & ~1;                                                   \
            int co = kc_ * 128 + zg * 16;                                       \
            short8 v0 = *(const short8*)(sHb + hr * 512 + (co ^ ((hr & 7) << 4))); \
            short8 v1 = *(const short8*)(sHb + (hr + 1) * 512 + (co ^ (((hr + 1) & 7) << 4))); \
            int4 zv; int* zp = (int*)&zv;                                       \
            _Pragma("unroll")                                                   \
            for (int jj = 0; jj < 4; ++jj) {                                    \
                float z0 = c.x * bf2f(v0[jj * 2])     + c.y * bf2f(v1[jj * 2]); \
                float z1 = c.x * bf2f(v0[jj * 2 + 1]) + c.y * bf2f(v1[jj * 2 + 1]); \
                zp[jj] = (int)pk2(z0, z1);                                      \
            }                                                                   \
            *(int4*)(sZb + (buf) * 8192 + zr * 128 + ((zg * 16) ^ ((zr & 7) << 4))) = zv; \
        }                                                                       \
    }

    floatx4 acc[4][4];
    #pragma unroll
    for (int i = 0; i < 4; ++i)
        #pragma unroll
        for (int j = 0; j < 4; ++j)
            acc[i][j] = (floatx4){0.f, 0.f, 0.f, 0.f};

    ZBUILD(0, 0);
    __syncthreads();

    int cur = 0;
    #pragma unroll 1
    for (int ch = 0; ch < 16; ++ch) {
        // B-frag loads for this chunk (L2-resident Wt2); latency covered by Zbuild
        short8 bfr[2][4];
        {
            int hh = ch >> 2, kc = ch & 3;
            #pragma unroll
            for (int ks = 0; ks < 2; ++ks) {
                const short* wb = (const short*)Wt2 +
                    (((hh * 8 + kc * 2 + ks) * 256 + wave * 64 + m) << 5) + q * 8;
                #pragma unroll
                for (int nt = 0; nt < 4; ++nt)
                    bfr[ks][nt] = *(const short8*)(wb + (nt << 9));
            }
        }
        // build next chunk into the other buffer (overlaps loads + MFMA)
        if (ch < 15) ZBUILD(ch + 1, cur ^ 1);
        // MFMA current chunk
        #pragma unroll
        for (int ks = 0; ks < 2; ++ks)
            #pragma unroll
            for (int mt = 0; mt < 4; ++mt) {
                int row = mt * 16 + m;
                short8 af = *(const short8*)(sZb + cur * 8192 + row * 128 +
                              ((ks * 64 + q * 16) ^ ((row & 7) << 4)));
                #pragma unroll
                for (int nt = 0; nt < 4; ++nt)
                    acc[mt][nt] = __builtin_amdgcn_mfma_f32_16x16x32_bf16(
                        af, bfr[ks][nt], acc[mt][nt], 0, 0, 0);
            }
        __syncthreads();
        cur ^= 1;
    }

    // epilogue: direct fp32 stores, 16 lanes = 64B contiguous per instruction
    {
        float* og = out + batch0 * 512;
        #pragma unroll
        for (int mt = 0; mt < 4; ++mt)
            #pragma unroll
            for (int nt = 0; nt < 4; ++nt) {
                int col = wave * 64 + nt * 16 + m;
                #pragma unroll
                for (int r = 0; r < 4; ++r)
                    og[(mt * 16 + q * 4 + r) * 256 + col] = acc[mt][nt][r];
            }
    }
    #undef ZBUILD
}

extern "C" void kernel_launch(void* const* d_in, const int* in_sizes, int n_in,
                              void* d_out, int out_size, void* d_ws, size_t ws_size,
                              hipStream_t stream) {
    const float* hin = (const float*)d_in[0];
    const int* adj   = (const int*)d_in[1];
    const float* W   = (const float*)d_in[2];
    const float* a   = (const float*)d_in[3];
    float* out       = (float*)d_out;

    __hip_bfloat16* PT  = (__hip_bfloat16*)d_ws;  // 16*256 bf16 = 8 KB
    __hip_bfloat16* Wt2 = PT + 16 * 256;          // 32*256*32 bf16 = 512 KB

    // ws guard: leaves out poisoned -> diagnostic, not corruption
    if (ws_size < (16 * 256 + 256 * 1024) * sizeof(__hip_bfloat16)) return;

    int B = in_sizes[0] / 512;                    // 65536
    gat_prep<<<1536, 256, 0, stream>>>(W, a, PT, Wt2);
    gat_main<<<B / TB, 256, 0, stream>>>(hin, adj, PT, Wt2, out);
}